// Round 1
// baseline (9535.653 us; speedup 1.0000x reference)
//
#include <hip/hip_runtime.h>
#include <math.h>

#define NN 65536
#define EE 1048576
#define ET (EE + NN)

__device__ __forceinline__ unsigned f2ord(float f) {
  unsigned u = __float_as_uint(f);
  return u ^ ((u & 0x80000000u) ? 0xFFFFFFFFu : 0x80000000u);
}
__device__ __forceinline__ float ord2f(unsigned u) {
  unsigned b = u ^ ((u & 0x80000000u) ? 0x80000000u : 0xFFFFFFFFu);
  return __uint_as_float(b);
}

// ---------------- dense: h = x@W, al_s/al_d, optional residual ----------------
template<int DIN, int DOUT, int H, bool HAS_RES>
__global__ __launch_bounds__(256) void gemm_al_kernel(
    const float* __restrict__ xin, const float* __restrict__ W,
    const float* __restrict__ asrc, const float* __restrict__ adst,
    const float* __restrict__ Aw, const float* __restrict__ Ab,
    float* __restrict__ hW, float* __restrict__ res,
    float* __restrict__ als, float* __restrict__ ald)
{
  int wave = threadIdx.x >> 6;
  int lane = threadIdx.x & 63;
  int node = blockIdx.x * 4 + wave;
  __shared__ float xs[4][DIN];
  const float* xrow = xin + (size_t)node * DIN;
  for (int k = lane; k < DIN; k += 64) xs[wave][k] = xrow[k];
  __syncthreads();
  if (lane < DOUT) {
    float h = 0.f, r = 0.f;
    #pragma unroll 4
    for (int k = 0; k < DIN; ++k) {
      float xv = xs[wave][k];
      h += xv * W[k * DOUT + lane];
      if (HAS_RES) r += xv * Aw[k * DOUT + lane];
    }
    hW[(size_t)node * DOUT + lane] = h;
    if (HAS_RES) res[(size_t)node * DOUT + lane] = r + Ab[lane];
    int head = lane >> 2, c = lane & 3;
    float ps = h * asrc[head * 4 + c];
    float pd = h * adst[head * 4 + c];
    ps += __shfl_xor(ps, 1); ps += __shfl_xor(ps, 2);
    pd += __shfl_xor(pd, 1); pd += __shfl_xor(pd, 2);
    if (c == 0) {
      als[(size_t)node * H + head] = ps;
      ald[(size_t)node * H + head] = pd;
    }
  }
}

// ---------------- edge pass 1: segment max (ordered-uint atomicMax) ----------------
template<int H>
__global__ __launch_bounds__(256) void edge_max_kernel(
    const int* __restrict__ ei, const float* __restrict__ als,
    const float* __restrict__ ald, unsigned* __restrict__ m)
{
  int e = blockIdx.x * blockDim.x + threadIdx.x;
  if (e >= ET) return;
  int s, d;
  if (e < EE) { s = ei[e]; d = ei[EE + e]; } else { s = d = e - EE; }
  const float* as_ = als + (size_t)s * H;
  const float* ad_ = ald + (size_t)d * H;
  #pragma unroll
  for (int h = 0; h < H; ++h) {
    float l = as_[h] + ad_[h];
    l = l > 0.f ? l : 0.2f * l;
    atomicMax(&m[(size_t)d * H + h], f2ord(l));
  }
}

__global__ __launch_bounds__(256) void decode_kernel(unsigned* m, int n) {
  int i = blockIdx.x * blockDim.x + threadIdx.x;
  if (i < n) ((float*)m)[i] = ord2f(m[i]);
}

// ---------------- edge pass 2: exp-sum ----------------
template<int H>
__global__ __launch_bounds__(256) void edge_sum_kernel(
    const int* __restrict__ ei, const float* __restrict__ als,
    const float* __restrict__ ald, const float* __restrict__ m,
    float* __restrict__ ssum)
{
  int e = blockIdx.x * blockDim.x + threadIdx.x;
  if (e >= ET) return;
  int s, d;
  if (e < EE) { s = ei[e]; d = ei[EE + e]; } else { s = d = e - EE; }
  const float* as_ = als + (size_t)s * H;
  const float* ad_ = ald + (size_t)d * H;
  #pragma unroll
  for (int h = 0; h < H; ++h) {
    float l = as_[h] + ad_[h];
    l = l > 0.f ? l : 0.2f * l;
    float ev = __expf(l - m[(size_t)d * H + h]);
    atomicAdd(&ssum[(size_t)d * H + h], ev);
  }
}

// ---------------- edge pass 3: alpha-weighted scatter + amean ----------------
template<int H>
__global__ __launch_bounds__(256) void edge_scatter_kernel(
    const int* __restrict__ ei, const float* __restrict__ als,
    const float* __restrict__ ald, const float* __restrict__ m,
    const float* __restrict__ ssum, const float* __restrict__ hW,
    float* __restrict__ agg, float* __restrict__ amean)
{
  int e = blockIdx.x * blockDim.x + threadIdx.x;
  if (e >= ET) return;
  int s, d;
  if (e < EE) { s = ei[e]; d = ei[EE + e]; } else { s = d = e - EE; }
  const float* as_ = als + (size_t)s * H;
  const float* ad_ = ald + (size_t)d * H;
  float asum = 0.f;
  #pragma unroll
  for (int h = 0; h < H; ++h) {
    float l = as_[h] + ad_[h];
    l = l > 0.f ? l : 0.2f * l;
    float alpha = __expf(l - m[(size_t)d * H + h]) / ssum[(size_t)d * H + h];
    asum += alpha;
    const float* hs = hW + ((size_t)s * H + h) * 4;
    float* ag = agg + ((size_t)d * H + h) * 4;
    #pragma unroll
    for (int c = 0; c < 4; ++c) atomicAdd(&ag[c], alpha * hs[c]);
  }
  if (e < EE) amean[e] = asum * (1.f / H);
}

// ---------------- post: elu -> layernorm -> (+res) ----------------
template<int DOUT, bool HAS_RES>
__global__ __launch_bounds__(256) void post_kernel(
    const float* __restrict__ agg, const float* __restrict__ bias,
    const float* __restrict__ g, const float* __restrict__ be,
    const float* __restrict__ res, float* __restrict__ out)
{
  int wave = threadIdx.x >> 6;
  int lane = threadIdx.x & 63;
  int node = blockIdx.x * 4 + wave;
  float v = 0.f;
  if (lane < DOUT) {
    v = agg[(size_t)node * DOUT + lane] + bias[lane];
    v = v > 0.f ? v : expm1f(v);  // elu
  }
  float sum = v;
  #pragma unroll
  for (int o = 32; o; o >>= 1) sum += __shfl_xor(sum, o);
  float mu = sum / DOUT;
  float dv = (lane < DOUT) ? (v - mu) : 0.f;
  float vs = dv * dv;
  #pragma unroll
  for (int o = 32; o; o >>= 1) vs += __shfl_xor(vs, o);
  float rstd = rsqrtf(vs / DOUT + 1e-5f);
  if (lane < DOUT) {
    float y = (v - mu) * rstd * g[lane] + be[lane];
    if (HAS_RES) y += res[(size_t)node * DOUT + lane];
    out[(size_t)node * DOUT + lane] = y;
  }
}

// ---------------- softmax over E edge-alpha means ----------------
__global__ __launch_bounds__(256) void reduce_max_kernel(
    const float* __restrict__ a, int n, unsigned* __restrict__ out)
{
  __shared__ float red[4];
  float v = -INFINITY;
  for (int i = blockIdx.x * blockDim.x + threadIdx.x; i < n; i += gridDim.x * blockDim.x)
    v = fmaxf(v, a[i]);
  #pragma unroll
  for (int o = 32; o; o >>= 1) v = fmaxf(v, __shfl_xor(v, o));
  if ((threadIdx.x & 63) == 0) red[threadIdx.x >> 6] = v;
  __syncthreads();
  if (threadIdx.x == 0) {
    float mx = fmaxf(fmaxf(red[0], red[1]), fmaxf(red[2], red[3]));
    atomicMax(out, f2ord(mx));
  }
}

__global__ __launch_bounds__(256) void reduce_sumexp_kernel(
    const float* __restrict__ a, int n, const unsigned* __restrict__ mx_u,
    float* __restrict__ out)
{
  __shared__ float red[4];
  float mx = ord2f(*mx_u);
  float s = 0.f;
  for (int i = blockIdx.x * blockDim.x + threadIdx.x; i < n; i += gridDim.x * blockDim.x)
    s += __expf(a[i] - mx);
  #pragma unroll
  for (int o = 32; o; o >>= 1) s += __shfl_xor(s, o);
  if ((threadIdx.x & 63) == 0) red[threadIdx.x >> 6] = s;
  __syncthreads();
  if (threadIdx.x == 0) atomicAdd(out, red[0] + red[1] + red[2] + red[3]);
}

__global__ __launch_bounds__(256) void write_softmax_kernel(
    const float* __restrict__ a, int n, const unsigned* __restrict__ mx_u,
    const float* __restrict__ ssum, float* __restrict__ out)
{
  float mx = ord2f(*mx_u);
  float inv = 1.f / *ssum;
  int i = blockIdx.x * blockDim.x + threadIdx.x;
  if (i < n) out[i] = __expf(a[i] - mx) * inv;
}

// ---------------- per-layer driver ----------------
template<int DIN, int DOUT, int H, bool HAS_RES>
static void run_layer(const float* xin, const float* W, const float* as_,
                      const float* ad_, const float* bias, const float* Aw,
                      const float* Ab, const float* g, const float* be,
                      const int* ei, float* hW, float* res, float* als,
                      float* ald, float* mbuf, float* sbuf, float* agg,
                      float* amean, float* scal, float* hout, float* eout,
                      hipStream_t stream)
{
  hipMemsetAsync(mbuf, 0, (size_t)NN * H * sizeof(float), stream);
  hipMemsetAsync(sbuf, 0, (size_t)NN * H * sizeof(float), stream);
  hipMemsetAsync(agg, 0, (size_t)NN * DOUT * sizeof(float), stream);
  hipMemsetAsync(scal, 0, 16, stream);

  gemm_al_kernel<DIN, DOUT, H, HAS_RES><<<NN / 4, 256, 0, stream>>>(
      xin, W, as_, ad_, Aw, Ab, hW, res, als, ald);
  edge_max_kernel<H><<<ET / 256, 256, 0, stream>>>(ei, als, ald, (unsigned*)mbuf);
  decode_kernel<<<(NN * H) / 256, 256, 0, stream>>>((unsigned*)mbuf, NN * H);
  edge_sum_kernel<H><<<ET / 256, 256, 0, stream>>>(ei, als, ald, mbuf, sbuf);
  edge_scatter_kernel<H><<<ET / 256, 256, 0, stream>>>(ei, als, ald, mbuf, sbuf,
                                                       hW, agg, amean);
  post_kernel<DOUT, HAS_RES><<<NN / 4, 256, 0, stream>>>(agg, bias, g, be, res, hout);

  reduce_max_kernel<<<256, 256, 0, stream>>>(amean, EE, (unsigned*)scal);
  reduce_sumexp_kernel<<<256, 256, 0, stream>>>(amean, EE, (unsigned*)scal, scal + 1);
  write_softmax_kernel<<<EE / 256, 256, 0, stream>>>(amean, EE, (unsigned*)scal,
                                                     scal + 1, eout);
}

extern "C" void kernel_launch(void* const* d_in, const int* in_sizes, int n_in,
                              void* d_out, int out_size, void* d_ws, size_t ws_size,
                              hipStream_t stream)
{
  const float* x   = (const float*)d_in[0];
  const int*   ei  = (const int*)d_in[1];
  const float* W1  = (const float*)d_in[3];
  const float* as1 = (const float*)d_in[4];
  const float* ad1 = (const float*)d_in[5];
  const float* b1  = (const float*)d_in[6];
  const float* W2  = (const float*)d_in[7];
  const float* as2 = (const float*)d_in[8];
  const float* ad2 = (const float*)d_in[9];
  const float* b2  = (const float*)d_in[10];
  const float* W3  = (const float*)d_in[11];
  const float* as3 = (const float*)d_in[12];
  const float* ad3 = (const float*)d_in[13];
  const float* b3  = (const float*)d_in[14];
  const float* A1w = (const float*)d_in[15];
  const float* A1b = (const float*)d_in[16];
  const float* A2w = (const float*)d_in[17];
  const float* A2b = (const float*)d_in[18];
  const float* g1  = (const float*)d_in[19];
  const float* be1 = (const float*)d_in[20];
  const float* g2  = (const float*)d_in[21];
  const float* be2 = (const float*)d_in[22];
  const float* g3  = (const float*)d_in[23];
  const float* be3 = (const float*)d_in[24];

  float* ws = (float*)d_ws;
  size_t off = 0;
  float* h1    = ws + off; off += (size_t)NN * 64;
  float* h2    = ws + off; off += (size_t)NN * 32;
  float* hW    = ws + off; off += (size_t)NN * 64;
  float* res   = ws + off; off += (size_t)NN * 64;
  float* als   = ws + off; off += (size_t)NN * 16;
  float* ald   = ws + off; off += (size_t)NN * 16;
  float* mbuf  = ws + off; off += (size_t)NN * 16;
  float* sbuf  = ws + off; off += (size_t)NN * 16;
  float* agg   = ws + off; off += (size_t)NN * 64;
  float* amean = ws + off; off += (size_t)EE;
  float* scal  = ws + off; off += 16;

  float* outh3 = (float*)d_out;
  float* oute1 = outh3 + (size_t)NN * 16;
  float* oute2 = oute1 + EE;
  float* oute3 = oute2 + EE;

  run_layer<84, 64, 16, true>(x, W1, as1, ad1, b1, A1w, A1b, g1, be1, ei,
                              hW, res, als, ald, mbuf, sbuf, agg, amean, scal,
                              h1, oute1, stream);
  run_layer<64, 32, 8, true>(h1, W2, as2, ad2, b2, A2w, A2b, g2, be2, ei,
                             hW, res, als, ald, mbuf, sbuf, agg, amean, scal,
                             h2, oute2, stream);
  run_layer<32, 16, 4, false>(h2, W3, as3, ad3, b3, nullptr, nullptr, g3, be3, ei,
                              hW, res, als, ald, mbuf, sbuf, agg, amean, scal,
                              outh3, oute3, stream);
}

// Round 2
// 887.615 us; speedup vs baseline: 10.7430x; 10.7430x over previous
//
#include <hip/hip_runtime.h>
#include <math.h>

#define NN 65536
#define EE 1048576
#define ET (EE + NN)

__device__ __forceinline__ unsigned f2ord(float f) {
  unsigned u = __float_as_uint(f);
  return u ^ ((u & 0x80000000u) ? 0xFFFFFFFFu : 0x80000000u);
}
__device__ __forceinline__ float ord2f(unsigned u) {
  unsigned b = u ^ ((u & 0x80000000u) ? 0x80000000u : 0xFFFFFFFFu);
  return __uint_as_float(b);
}

// ---------------- CSR build (by destination) ----------------
__global__ __launch_bounds__(256) void count_kernel(const int* __restrict__ ei,
                                                    int* __restrict__ cnt) {
  int e = blockIdx.x * 256 + threadIdx.x;
  if (e >= ET) return;
  int d = (e < EE) ? ei[EE + e] : e - EE;
  atomicAdd(&cnt[d], 1);
}

// exclusive scan of cnt[NN] -> row_ptr[NN+1]; single block of 1024 threads
__global__ __launch_bounds__(1024) void scan_kernel(const int* __restrict__ cnt,
                                                    int* __restrict__ row_ptr) {
  __shared__ int part[1024];
  int t = threadIdx.x;
  int base = t * 64;
  int s = 0;
  #pragma unroll 8
  for (int i = 0; i < 64; ++i) s += cnt[base + i];
  part[t] = s;
  __syncthreads();
  for (int off = 1; off < 1024; off <<= 1) {
    int v = (t >= off) ? part[t - off] : 0;
    __syncthreads();
    if (t >= off) part[t] += v;
    __syncthreads();
  }
  int run = (t > 0) ? part[t - 1] : 0;
  for (int i = 0; i < 64; ++i) {
    row_ptr[base + i] = run;
    run += cnt[base + i];
  }
  if (t == 1023) row_ptr[NN] = part[1023];
}

__global__ __launch_bounds__(256) void init_cur_kernel(const int* __restrict__ row_ptr,
                                                       int* __restrict__ cur) {
  int i = blockIdx.x * 256 + threadIdx.x;
  if (i < NN) cur[i] = row_ptr[i];
}

__global__ __launch_bounds__(256) void fill_kernel(const int* __restrict__ ei,
                                                   int* __restrict__ cur,
                                                   int* __restrict__ col,
                                                   int* __restrict__ orig) {
  int e = blockIdx.x * 256 + threadIdx.x;
  if (e >= ET) return;
  int s, d;
  if (e < EE) { s = ei[e]; d = ei[EE + e]; } else { s = d = e - EE; }
  int pos = atomicAdd(&cur[d], 1);
  col[pos] = s;
  orig[pos] = e;
}

// ---------------- dense: h = x@W, al_s/al_d, optional residual ----------------
template<int DIN, int DOUT, int H, bool HAS_RES>
__global__ __launch_bounds__(256) void gemm_al_kernel(
    const float* __restrict__ xin, const float* __restrict__ W,
    const float* __restrict__ asrc, const float* __restrict__ adst,
    const float* __restrict__ Aw, const float* __restrict__ Ab,
    float* __restrict__ hW, float* __restrict__ res,
    float* __restrict__ als, float* __restrict__ ald)
{
  int wave = threadIdx.x >> 6;
  int lane = threadIdx.x & 63;
  int node = blockIdx.x * 4 + wave;
  __shared__ float xs[4][DIN];
  const float* xrow = xin + (size_t)node * DIN;
  for (int k = lane; k < DIN; k += 64) xs[wave][k] = xrow[k];
  __syncthreads();
  if (lane < DOUT) {
    float h = 0.f, r = 0.f;
    #pragma unroll 4
    for (int k = 0; k < DIN; ++k) {
      float xv = xs[wave][k];
      h += xv * W[k * DOUT + lane];
      if (HAS_RES) r += xv * Aw[k * DOUT + lane];
    }
    hW[(size_t)node * DOUT + lane] = h;
    if (HAS_RES) res[(size_t)node * DOUT + lane] = r + Ab[lane];
    int head = lane >> 2, c = lane & 3;
    float ps = h * asrc[head * 4 + c];
    float pd = h * adst[head * 4 + c];
    ps += __shfl_xor(ps, 1); ps += __shfl_xor(ps, 2);
    pd += __shfl_xor(pd, 1); pd += __shfl_xor(pd, 2);
    if (c == 0) {
      als[(size_t)node * H + head] = ps;
      ald[(size_t)node * H + head] = pd;
    }
  }
}

// ---------------- fused gather: softmax over in-edges + agg + elu + LN + res ----------------
template<int DOUT, int H, bool HAS_RES>
__global__ __launch_bounds__(256) void gat_gather_kernel(
    const int* __restrict__ row_ptr, const int* __restrict__ col,
    const int* __restrict__ orig,
    const float* __restrict__ als, const float* __restrict__ ald,
    const float* __restrict__ hW,
    const float* __restrict__ bias, const float* __restrict__ g,
    const float* __restrict__ be, const float* __restrict__ res,
    float* __restrict__ out, float* __restrict__ amean)
{
  int tid = blockIdx.x * 256 + threadIdx.x;
  int node = tid / DOUT;
  int l = threadIdx.x % DOUT;          // lane within DOUT-group (groups aligned)
  int h = l >> 2, c = l & 3;

  int r0 = row_ptr[node], r1 = row_ptr[node + 1];
  float ald_h = ald[(size_t)node * H + h];

  // pass 1a: per-head max (4 lanes of a head split edges, stride 4)
  float m = -INFINITY;
  for (int e = r0 + c; e < r1; e += 4) {
    int s = col[e];
    float lg = als[(size_t)s * H + h] + ald_h;
    lg = lg > 0.f ? lg : 0.2f * lg;
    m = fmaxf(m, lg);
  }
  m = fmaxf(m, __shfl_xor(m, 1));
  m = fmaxf(m, __shfl_xor(m, 2));

  // pass 1b: per-head exp-sum
  float ssum = 0.f;
  for (int e = r0 + c; e < r1; e += 4) {
    int s = col[e];
    float lg = als[(size_t)s * H + h] + ald_h;
    lg = lg > 0.f ? lg : 0.2f * lg;
    ssum += __expf(lg - m);
  }
  ssum += __shfl_xor(ssum, 1);
  ssum += __shfl_xor(ssum, 2);
  float inv_s = 1.f / ssum;

  // pass 2: weighted aggregation + per-edge head-mean alpha
  float acc = 0.f;
  for (int e = r0; e < r1; ++e) {
    int s = col[e];
    float lg = als[(size_t)s * H + h] + ald_h;
    lg = lg > 0.f ? lg : 0.2f * lg;
    float alpha = __expf(lg - m) * inv_s;
    acc += alpha * hW[(size_t)s * DOUT + l];
    float asum = alpha;              // sum over DOUT lanes = 4 * sum_h alpha
    #pragma unroll
    for (int o = DOUT / 2; o; o >>= 1) asum += __shfl_xor(asum, o);
    if (l == 0) {
      int oe = orig[e];
      if (oe < EE) amean[oe] = asum * (1.f / DOUT);  // = sum_h alpha / H
    }
  }

  // epilogue: bias -> elu -> layernorm -> (+res)
  float v = acc + bias[l];
  v = v > 0.f ? v : expm1f(v);
  float sum = v;
  #pragma unroll
  for (int o = DOUT / 2; o; o >>= 1) sum += __shfl_xor(sum, o);
  float mu = sum * (1.f / DOUT);
  float dv = v - mu;
  float vs = dv * dv;
  #pragma unroll
  for (int o = DOUT / 2; o; o >>= 1) vs += __shfl_xor(vs, o);
  float rstd = rsqrtf(vs * (1.f / DOUT) + 1e-5f);
  float y = dv * rstd * g[l] + be[l];
  if (HAS_RES) y += res[(size_t)node * DOUT + l];
  out[(size_t)node * DOUT + l] = y;
}

// ---------------- softmax over E edge-alpha means ----------------
__global__ __launch_bounds__(256) void reduce_max_kernel(
    const float* __restrict__ a, int n, unsigned* __restrict__ out)
{
  __shared__ float red[4];
  float v = -INFINITY;
  for (int i = blockIdx.x * blockDim.x + threadIdx.x; i < n; i += gridDim.x * blockDim.x)
    v = fmaxf(v, a[i]);
  #pragma unroll
  for (int o = 32; o; o >>= 1) v = fmaxf(v, __shfl_xor(v, o));
  if ((threadIdx.x & 63) == 0) red[threadIdx.x >> 6] = v;
  __syncthreads();
  if (threadIdx.x == 0) {
    float mx = fmaxf(fmaxf(red[0], red[1]), fmaxf(red[2], red[3]));
    atomicMax(out, f2ord(mx));
  }
}

__global__ __launch_bounds__(256) void reduce_sumexp_kernel(
    const float* __restrict__ a, int n, const unsigned* __restrict__ mx_u,
    float* __restrict__ out)
{
  __shared__ float red[4];
  float mx = ord2f(*mx_u);
  float s = 0.f;
  for (int i = blockIdx.x * blockDim.x + threadIdx.x; i < n; i += gridDim.x * blockDim.x)
    s += __expf(a[i] - mx);
  #pragma unroll
  for (int o = 32; o; o >>= 1) s += __shfl_xor(s, o);
  if ((threadIdx.x & 63) == 0) red[threadIdx.x >> 6] = s;
  __syncthreads();
  if (threadIdx.x == 0) atomicAdd(out, red[0] + red[1] + red[2] + red[3]);
}

__global__ __launch_bounds__(256) void write_softmax_kernel(
    const float* __restrict__ a, int n, const unsigned* __restrict__ mx_u,
    const float* __restrict__ ssum, float* __restrict__ out)
{
  float mx = ord2f(*mx_u);
  float inv = 1.f / *ssum;
  int i = blockIdx.x * blockDim.x + threadIdx.x;
  if (i < n) out[i] = __expf(a[i] - mx) * inv;
}

// ---------------- per-layer driver ----------------
template<int DIN, int DOUT, int H, bool HAS_RES>
static void run_layer(const float* xin, const float* W, const float* as_,
                      const float* ad_, const float* bias, const float* Aw,
                      const float* Ab, const float* g, const float* be,
                      const int* row_ptr, const int* col, const int* orig,
                      float* hW, float* res, float* als, float* ald,
                      float* amean, float* scal, float* hout, float* eout,
                      hipStream_t stream)
{
  hipMemsetAsync(scal, 0, 16, stream);
  gemm_al_kernel<DIN, DOUT, H, HAS_RES><<<NN / 4, 256, 0, stream>>>(
      xin, W, as_, ad_, Aw, Ab, hW, res, als, ald);
  gat_gather_kernel<DOUT, H, HAS_RES><<<(NN * DOUT) / 256, 256, 0, stream>>>(
      row_ptr, col, orig, als, ald, hW, bias, g, be, res, hout, amean);
  reduce_max_kernel<<<256, 256, 0, stream>>>(amean, EE, (unsigned*)scal);
  reduce_sumexp_kernel<<<256, 256, 0, stream>>>(amean, EE, (unsigned*)scal, scal + 1);
  write_softmax_kernel<<<EE / 256, 256, 0, stream>>>(amean, EE, (unsigned*)scal,
                                                     scal + 1, eout);
}

extern "C" void kernel_launch(void* const* d_in, const int* in_sizes, int n_in,
                              void* d_out, int out_size, void* d_ws, size_t ws_size,
                              hipStream_t stream)
{
  const float* x   = (const float*)d_in[0];
  const int*   ei  = (const int*)d_in[1];
  const float* W1  = (const float*)d_in[3];
  const float* as1 = (const float*)d_in[4];
  const float* ad1 = (const float*)d_in[5];
  const float* b1  = (const float*)d_in[6];
  const float* W2  = (const float*)d_in[7];
  const float* as2 = (const float*)d_in[8];
  const float* ad2 = (const float*)d_in[9];
  const float* b2  = (const float*)d_in[10];
  const float* W3  = (const float*)d_in[11];
  const float* as3 = (const float*)d_in[12];
  const float* ad3 = (const float*)d_in[13];
  const float* b3  = (const float*)d_in[14];
  const float* A1w = (const float*)d_in[15];
  const float* A1b = (const float*)d_in[16];
  const float* A2w = (const float*)d_in[17];
  const float* A2b = (const float*)d_in[18];
  const float* g1  = (const float*)d_in[19];
  const float* be1 = (const float*)d_in[20];
  const float* g2  = (const float*)d_in[21];
  const float* be2 = (const float*)d_in[22];
  const float* g3  = (const float*)d_in[23];
  const float* be3 = (const float*)d_in[24];

  float* ws = (float*)d_ws;
  size_t off = 0;
  float* h1    = ws + off; off += (size_t)NN * 64;
  float* h2    = ws + off; off += (size_t)NN * 32;
  float* hW    = ws + off; off += (size_t)NN * 64;
  float* res   = ws + off; off += (size_t)NN * 64;
  float* als   = ws + off; off += (size_t)NN * 16;
  float* ald   = ws + off; off += (size_t)NN * 16;
  float* amean = ws + off; off += (size_t)EE;
  float* scal  = ws + off; off += 16;
  int* cnt     = (int*)(ws + off); off += NN;
  int* row_ptr = (int*)(ws + off); off += NN + 4;
  int* cur     = (int*)(ws + off); off += NN;
  int* col     = (int*)(ws + off); off += ET;
  int* orig    = (int*)(ws + off); off += ET;

  float* outh3 = (float*)d_out;
  float* oute1 = outh3 + (size_t)NN * 16;
  float* oute2 = oute1 + EE;
  float* oute3 = oute2 + EE;

  // ---- CSR build (once per call; graph-capture safe) ----
  hipMemsetAsync(cnt, 0, NN * sizeof(int), stream);
  count_kernel<<<ET / 256, 256, 0, stream>>>(ei, cnt);
  scan_kernel<<<1, 1024, 0, stream>>>(cnt, row_ptr);
  init_cur_kernel<<<NN / 256, 256, 0, stream>>>(row_ptr, cur);
  fill_kernel<<<ET / 256, 256, 0, stream>>>(ei, cur, col, orig);

  run_layer<84, 64, 16, true>(x, W1, as1, ad1, b1, A1w, A1b, g1, be1,
                              row_ptr, col, orig, hW, res, als, ald,
                              amean, scal, h1, oute1, stream);
  run_layer<64, 32, 8, true>(h1, W2, as2, ad2, b2, A2w, A2b, g2, be2,
                             row_ptr, col, orig, hW, res, als, ald,
                             amean, scal, h2, oute2, stream);
  run_layer<32, 16, 4, false>(h2, W3, as3, ad3, b3, nullptr, nullptr, g3, be3,
                              row_ptr, col, orig, hW, res, als, ald,
                              amean, scal, outh3, oute3, stream);
}

// Round 3
// 631.060 us; speedup vs baseline: 15.1105x; 1.4065x over previous
//
#include <hip/hip_runtime.h>
#include <math.h>

#define NN 65536
#define EE 1048576
#define ET (EE + NN)

__device__ __forceinline__ unsigned f2ord(float f) {
  unsigned u = __float_as_uint(f);
  return u ^ ((u & 0x80000000u) ? 0xFFFFFFFFu : 0x80000000u);
}
__device__ __forceinline__ float ord2f(unsigned u) {
  unsigned b = u ^ ((u & 0x80000000u) ? 0x80000000u : 0xFFFFFFFFu);
  return __uint_as_float(b);
}

// ---------------- CSR build (by destination) ----------------
__global__ __launch_bounds__(256) void count_kernel(const int* __restrict__ ei,
                                                    int* __restrict__ cnt) {
  int e = blockIdx.x * 256 + threadIdx.x;
  if (e >= ET) return;
  int d = (e < EE) ? ei[EE + e] : e - EE;
  atomicAdd(&cnt[d], 1);
}

// exclusive scan of cnt[NN] -> row_ptr[NN+1]; single block of 1024 threads
__global__ __launch_bounds__(1024) void scan_kernel(const int* __restrict__ cnt,
                                                    int* __restrict__ row_ptr) {
  __shared__ int part[1024];
  int t = threadIdx.x;
  int base = t * 64;
  int s = 0;
  #pragma unroll 8
  for (int i = 0; i < 64; ++i) s += cnt[base + i];
  part[t] = s;
  __syncthreads();
  for (int off = 1; off < 1024; off <<= 1) {
    int v = (t >= off) ? part[t - off] : 0;
    __syncthreads();
    if (t >= off) part[t] += v;
    __syncthreads();
  }
  int run = (t > 0) ? part[t - 1] : 0;
  for (int i = 0; i < 64; ++i) {
    row_ptr[base + i] = run;
    run += cnt[base + i];
  }
  if (t == 1023) row_ptr[NN] = part[1023];
}

__global__ __launch_bounds__(256) void init_cur_kernel(const int* __restrict__ row_ptr,
                                                       int* __restrict__ cur) {
  int i = blockIdx.x * 256 + threadIdx.x;
  if (i < NN) cur[i] = row_ptr[i];
}

__global__ __launch_bounds__(256) void fill_kernel(const int* __restrict__ ei,
                                                   int* __restrict__ cur,
                                                   int* __restrict__ col) {
  int e = blockIdx.x * 256 + threadIdx.x;
  if (e >= ET) return;
  int s, d;
  if (e < EE) { s = ei[e]; d = ei[EE + e]; } else { s = d = e - EE; }
  int pos = atomicAdd(&cur[d], 1);
  col[pos] = s;
}

// ---------------- dense: h = x@W, al_s/al_d, optional residual ----------------
template<int DIN, int DOUT, int H, bool HAS_RES>
__global__ __launch_bounds__(256) void gemm_al_kernel(
    const float* __restrict__ xin, const float* __restrict__ W,
    const float* __restrict__ asrc, const float* __restrict__ adst,
    const float* __restrict__ Aw, const float* __restrict__ Ab,
    float* __restrict__ hW, float* __restrict__ res,
    float* __restrict__ als, float* __restrict__ ald)
{
  int wave = threadIdx.x >> 6;
  int lane = threadIdx.x & 63;
  int node = blockIdx.x * 4 + wave;
  __shared__ float xs[4][DIN];
  const float* xrow = xin + (size_t)node * DIN;
  for (int k = lane; k < DIN; k += 64) xs[wave][k] = xrow[k];
  __syncthreads();
  if (lane < DOUT) {
    float h = 0.f, r = 0.f;
    #pragma unroll 4
    for (int k = 0; k < DIN; ++k) {
      float xv = xs[wave][k];
      h += xv * W[k * DOUT + lane];
      if (HAS_RES) r += xv * Aw[k * DOUT + lane];
    }
    hW[(size_t)node * DOUT + lane] = h;
    if (HAS_RES) res[(size_t)node * DOUT + lane] = r + Ab[lane];
    int head = lane >> 2, c = lane & 3;
    float ps = h * asrc[head * 4 + c];
    float pd = h * adst[head * 4 + c];
    ps += __shfl_xor(ps, 1); ps += __shfl_xor(ps, 2);
    pd += __shfl_xor(pd, 1); pd += __shfl_xor(pd, 2);
    if (c == 0) {
      als[(size_t)node * H + head] = ps;
      ald[(size_t)node * H + head] = pd;
    }
  }
}

// ---------------- fused gather: single pass, unnormalized accumulate ----------------
// out_l = (sum_e exp(lg_h(e)) * hW[s_e][l]) / (sum_e exp(lg_h(e))); epilogue fused.
template<int DOUT, int H, bool HAS_RES>
__global__ __launch_bounds__(256) void gat_gather_kernel(
    const int* __restrict__ row_ptr, const int* __restrict__ col,
    const float* __restrict__ als, const float* __restrict__ ald,
    const float* __restrict__ hW,
    const float* __restrict__ bias, const float* __restrict__ g,
    const float* __restrict__ be, const float* __restrict__ res,
    float* __restrict__ out, float* __restrict__ inv_s_out)
{
  int tid = blockIdx.x * 256 + threadIdx.x;
  int node = tid / DOUT;
  int l = threadIdx.x % DOUT;   // lane within DOUT-group (aligned in wave)
  int h = l >> 2;

  int r0 = row_ptr[node], r1 = row_ptr[node + 1];
  float ald_h = ald[(size_t)node * H + h];

  float acc = 0.f, ss = 0.f;
  int e = r0;
  for (; e + 1 < r1; e += 2) {       // 2-wide for memory-level parallelism
    int s0 = col[e], s1 = col[e + 1];
    float av0 = als[(size_t)s0 * H + h];
    float hv0 = hW[(size_t)s0 * DOUT + l];
    float av1 = als[(size_t)s1 * H + h];
    float hv1 = hW[(size_t)s1 * DOUT + l];
    float lg0 = av0 + ald_h; lg0 = lg0 > 0.f ? lg0 : 0.2f * lg0;
    float lg1 = av1 + ald_h; lg1 = lg1 > 0.f ? lg1 : 0.2f * lg1;
    float e0 = __expf(lg0), e1 = __expf(lg1);
    ss += e0 + e1;
    acc += e0 * hv0 + e1 * hv1;
  }
  if (e < r1) {
    int s0 = col[e];
    float av0 = als[(size_t)s0 * H + h];
    float hv0 = hW[(size_t)s0 * DOUT + l];
    float lg0 = av0 + ald_h; lg0 = lg0 > 0.f ? lg0 : 0.2f * lg0;
    float e0 = __expf(lg0);
    ss += e0;
    acc += e0 * hv0;
  }

  float inv = 1.f / ss;               // identical across the 4 lanes of a head
  if ((l & 3) == 0) inv_s_out[(size_t)node * H + h] = inv;

  // epilogue: normalize -> bias -> elu -> layernorm -> (+res)
  float v = acc * inv + bias[l];
  v = v > 0.f ? v : expm1f(v);
  float sum = v;
  #pragma unroll
  for (int o = DOUT / 2; o; o >>= 1) sum += __shfl_xor(sum, o);
  float mu = sum * (1.f / DOUT);
  float dv = v - mu;
  float vs = dv * dv;
  #pragma unroll
  for (int o = DOUT / 2; o; o >>= 1) vs += __shfl_xor(vs, o);
  float rstd = rsqrtf(vs * (1.f / DOUT) + 1e-5f);
  float y = dv * rstd * g[l] + be[l];
  if (HAS_RES) y += res[(size_t)node * DOUT + l];
  out[(size_t)node * DOUT + l] = y;
}

// ---------------- per-edge head-mean alpha (original edge order, coalesced) --------
template<int H>
__global__ __launch_bounds__(256) void amean_kernel(
    const int* __restrict__ ei, const float* __restrict__ als,
    const float* __restrict__ ald, const float* __restrict__ inv_s,
    float* __restrict__ amean)
{
  int e = blockIdx.x * 256 + threadIdx.x;
  if (e >= EE) return;
  int s = ei[e], d = ei[EE + e];
  const float* as_ = als + (size_t)s * H;
  const float* ad_ = ald + (size_t)d * H;
  const float* iv_ = inv_s + (size_t)d * H;
  float t = 0.f;
  #pragma unroll
  for (int h = 0; h < H; ++h) {
    float lg = as_[h] + ad_[h];
    lg = lg > 0.f ? lg : 0.2f * lg;
    t += __expf(lg) * iv_[h];
  }
  amean[e] = t * (1.f / H);
}

// ---------------- softmax over E edge-alpha means ----------------
__global__ __launch_bounds__(256) void reduce_max_kernel(
    const float* __restrict__ a, int n, unsigned* __restrict__ out)
{
  __shared__ float red[4];
  float v = -INFINITY;
  for (int i = blockIdx.x * blockDim.x + threadIdx.x; i < n; i += gridDim.x * blockDim.x)
    v = fmaxf(v, a[i]);
  #pragma unroll
  for (int o = 32; o; o >>= 1) v = fmaxf(v, __shfl_xor(v, o));
  if ((threadIdx.x & 63) == 0) red[threadIdx.x >> 6] = v;
  __syncthreads();
  if (threadIdx.x == 0) {
    float mx = fmaxf(fmaxf(red[0], red[1]), fmaxf(red[2], red[3]));
    atomicMax(out, f2ord(mx));
  }
}

__global__ __launch_bounds__(256) void reduce_sumexp_kernel(
    const float* __restrict__ a, int n, const unsigned* __restrict__ mx_u,
    float* __restrict__ out)
{
  __shared__ float red[4];
  float mx = ord2f(*mx_u);
  float s = 0.f;
  for (int i = blockIdx.x * blockDim.x + threadIdx.x; i < n; i += gridDim.x * blockDim.x)
    s += __expf(a[i] - mx);
  #pragma unroll
  for (int o = 32; o; o >>= 1) s += __shfl_xor(s, o);
  if ((threadIdx.x & 63) == 0) red[threadIdx.x >> 6] = s;
  __syncthreads();
  if (threadIdx.x == 0) atomicAdd(out, red[0] + red[1] + red[2] + red[3]);
}

__global__ __launch_bounds__(256) void write_softmax_kernel(
    const float* __restrict__ a, int n, const unsigned* __restrict__ mx_u,
    const float* __restrict__ ssum, float* __restrict__ out)
{
  float mx = ord2f(*mx_u);
  float inv = 1.f / *ssum;
  int i = blockIdx.x * blockDim.x + threadIdx.x;
  if (i < n) out[i] = __expf(a[i] - mx) * inv;
}

// ---------------- per-layer driver ----------------
template<int DIN, int DOUT, int H, bool HAS_RES>
static void run_layer(const float* xin, const float* W, const float* as_,
                      const float* ad_, const float* bias, const float* Aw,
                      const float* Ab, const float* g, const float* be,
                      const int* ei, const int* row_ptr, const int* col,
                      float* hW, float* res, float* als, float* ald,
                      float* inv_s, float* amean, float* scal,
                      float* hout, float* eout, hipStream_t stream)
{
  hipMemsetAsync(scal, 0, 16, stream);
  gemm_al_kernel<DIN, DOUT, H, HAS_RES><<<NN / 4, 256, 0, stream>>>(
      xin, W, as_, ad_, Aw, Ab, hW, res, als, ald);
  gat_gather_kernel<DOUT, H, HAS_RES><<<(NN * DOUT) / 256, 256, 0, stream>>>(
      row_ptr, col, als, ald, hW, bias, g, be, res, hout, inv_s);
  amean_kernel<H><<<EE / 256, 256, 0, stream>>>(ei, als, ald, inv_s, amean);
  reduce_max_kernel<<<256, 256, 0, stream>>>(amean, EE, (unsigned*)scal);
  reduce_sumexp_kernel<<<256, 256, 0, stream>>>(amean, EE, (unsigned*)scal, scal + 1);
  write_softmax_kernel<<<EE / 256, 256, 0, stream>>>(amean, EE, (unsigned*)scal,
                                                     scal + 1, eout);
}

extern "C" void kernel_launch(void* const* d_in, const int* in_sizes, int n_in,
                              void* d_out, int out_size, void* d_ws, size_t ws_size,
                              hipStream_t stream)
{
  const float* x   = (const float*)d_in[0];
  const int*   ei  = (const int*)d_in[1];
  const float* W1  = (const float*)d_in[3];
  const float* as1 = (const float*)d_in[4];
  const float* ad1 = (const float*)d_in[5];
  const float* b1  = (const float*)d_in[6];
  const float* W2  = (const float*)d_in[7];
  const float* as2 = (const float*)d_in[8];
  const float* ad2 = (const float*)d_in[9];
  const float* b2  = (const float*)d_in[10];
  const float* W3  = (const float*)d_in[11];
  const float* as3 = (const float*)d_in[12];
  const float* ad3 = (const float*)d_in[13];
  const float* b3  = (const float*)d_in[14];
  const float* A1w = (const float*)d_in[15];
  const float* A1b = (const float*)d_in[16];
  const float* A2w = (const float*)d_in[17];
  const float* A2b = (const float*)d_in[18];
  const float* g1  = (const float*)d_in[19];
  const float* be1 = (const float*)d_in[20];
  const float* g2  = (const float*)d_in[21];
  const float* be2 = (const float*)d_in[22];
  const float* g3  = (const float*)d_in[23];
  const float* be3 = (const float*)d_in[24];

  float* ws = (float*)d_ws;
  size_t off = 0;
  float* h1    = ws + off; off += (size_t)NN * 64;
  float* h2    = ws + off; off += (size_t)NN * 32;
  float* hW    = ws + off; off += (size_t)NN * 64;
  float* res   = ws + off; off += (size_t)NN * 64;
  float* als   = ws + off; off += (size_t)NN * 16;
  float* ald   = ws + off; off += (size_t)NN * 16;
  float* inv_s = ws + off; off += (size_t)NN * 16;
  float* amean = ws + off; off += (size_t)EE;
  float* scal  = ws + off; off += 16;
  int* cnt     = (int*)(ws + off); off += NN;
  int* row_ptr = (int*)(ws + off); off += NN + 4;
  int* cur     = (int*)(ws + off); off += NN;
  int* col     = (int*)(ws + off); off += ET;

  float* outh3 = (float*)d_out;
  float* oute1 = outh3 + (size_t)NN * 16;
  float* oute2 = oute1 + EE;
  float* oute3 = oute2 + EE;

  // ---- CSR build (once per call; graph-capture safe) ----
  hipMemsetAsync(cnt, 0, NN * sizeof(int), stream);
  count_kernel<<<ET / 256, 256, 0, stream>>>(ei, cnt);
  scan_kernel<<<1, 1024, 0, stream>>>(cnt, row_ptr);
  init_cur_kernel<<<NN / 256, 256, 0, stream>>>(row_ptr, cur);
  fill_kernel<<<ET / 256, 256, 0, stream>>>(ei, cur, col);

  run_layer<84, 64, 16, true>(x, W1, as1, ad1, b1, A1w, A1b, g1, be1,
                              ei, row_ptr, col, hW, res, als, ald,
                              inv_s, amean, scal, h1, oute1, stream);
  run_layer<64, 32, 8, true>(h1, W2, as2, ad2, b2, A2w, A2b, g2, be2,
                             ei, row_ptr, col, hW, res, als, ald,
                             inv_s, amean, scal, h2, oute2, stream);
  run_layer<32, 16, 4, false>(h2, W3, as3, ad3, b3, nullptr, nullptr, g3, be3,
                              ei, row_ptr, col, hW, res, als, ald,
                              inv_s, amean, scal, outh3, oute3, stream);
}

// Round 4
// 530.206 us; speedup vs baseline: 17.9848x; 1.1902x over previous
//
#include <hip/hip_runtime.h>
#include <math.h>

#define NN 65536
#define EE 1048576
#define ET (EE + NN)

// ---------------- CSR build (by destination) ----------------
__global__ __launch_bounds__(256) void count_kernel(const int* __restrict__ ei,
                                                    int* __restrict__ cnt) {
  int e = blockIdx.x * 256 + threadIdx.x;
  if (e >= ET) return;
  int d = (e < EE) ? ei[EE + e] : e - EE;
  atomicAdd(&cnt[d], 1);
}

// exclusive scan of cnt[NN] -> row_ptr[NN+1]; single block of 1024 threads
__global__ __launch_bounds__(1024) void scan_kernel(const int* __restrict__ cnt,
                                                    int* __restrict__ row_ptr) {
  __shared__ int part[1024];
  int t = threadIdx.x;
  int base = t * 64;
  int s = 0;
  #pragma unroll 8
  for (int i = 0; i < 64; ++i) s += cnt[base + i];
  part[t] = s;
  __syncthreads();
  for (int off = 1; off < 1024; off <<= 1) {
    int v = (t >= off) ? part[t - off] : 0;
    __syncthreads();
    if (t >= off) part[t] += v;
    __syncthreads();
  }
  int run = (t > 0) ? part[t - 1] : 0;
  for (int i = 0; i < 64; ++i) {
    row_ptr[base + i] = run;
    run += cnt[base + i];
  }
  if (t == 1023) row_ptr[NN] = part[1023];
}

__global__ __launch_bounds__(256) void init_cur_kernel(const int* __restrict__ row_ptr,
                                                       int* __restrict__ cur) {
  int i = blockIdx.x * 256 + threadIdx.x;
  if (i < NN) cur[i] = row_ptr[i];
}

__global__ __launch_bounds__(256) void fill_kernel(const int* __restrict__ ei,
                                                   int* __restrict__ cur,
                                                   int* __restrict__ col) {
  int e = blockIdx.x * 256 + threadIdx.x;
  if (e >= ET) return;
  int s, d;
  if (e < EE) { s = ei[e]; d = ei[EE + e]; } else { s = d = e - EE; }
  int pos = atomicAdd(&cur[d], 1);
  col[pos] = s;
}

// -------- dense: h = x@W, al_s/al_d, residual; register-blocked over nodes --------
// Each wave: NPW nodes per node-group, GPW=64/DOUT groups -> NPW*GPW nodes/wave.
template<int DIN, int DOUT, int H, bool HAS_RES, int NPW>
__global__ __launch_bounds__(256) void gemm_al_kernel(
    const float* __restrict__ xin, const float* __restrict__ W,
    const float* __restrict__ asrc, const float* __restrict__ adst,
    const float* __restrict__ Aw, const float* __restrict__ Ab,
    float* __restrict__ hW, float* __restrict__ res,
    float* __restrict__ als, float* __restrict__ ald)
{
  constexpr int GPW = 64 / DOUT;
  constexpr int NPB = 4 * NPW * GPW;   // nodes per block (4 waves)
  constexpr int DINP = DIN + 4;        // padded LDS stride (breaks pow2 bank alias)
  __shared__ float xs[NPB][DINP];

  int wave = threadIdx.x >> 6;
  int lane = threadIdx.x & 63;
  int l = lane % DOUT;                 // output column
  int sub = lane / DOUT;               // node-group within wave
  int block_base = blockIdx.x * NPB;

  // stage x tile (coalesced float4)
  {
    constexpr int NV = NPB * DIN / 4;
    const float4* xin4 = (const float4*)(xin + (size_t)block_base * DIN);
    for (int i = threadIdx.x; i < NV; i += 256) {
      float4 v = xin4[i];
      int flat = i * 4;
      int nd = flat / DIN, k = flat % DIN;
      *(float4*)&xs[nd][k] = v;
    }
  }
  __syncthreads();

  int nl = wave * (NPW * GPW) + sub * NPW;   // first local node for this lane
  float acc[NPW], racc[NPW];
  #pragma unroll
  for (int n = 0; n < NPW; ++n) { acc[n] = 0.f; racc[n] = 0.f; }

  for (int k = 0; k < DIN; k += 4) {
    float w0 = W[(k + 0) * DOUT + l];
    float w1 = W[(k + 1) * DOUT + l];
    float w2 = W[(k + 2) * DOUT + l];
    float w3 = W[(k + 3) * DOUT + l];
    float a0 = 0.f, a1 = 0.f, a2 = 0.f, a3 = 0.f;
    if (HAS_RES) {
      a0 = Aw[(k + 0) * DOUT + l];
      a1 = Aw[(k + 1) * DOUT + l];
      a2 = Aw[(k + 2) * DOUT + l];
      a3 = Aw[(k + 3) * DOUT + l];
    }
    #pragma unroll
    for (int n = 0; n < NPW; ++n) {
      float4 xv = *(const float4*)&xs[nl + n][k];
      acc[n] = fmaf(xv.x, w0, fmaf(xv.y, w1, fmaf(xv.z, w2, fmaf(xv.w, w3, acc[n]))));
      if (HAS_RES)
        racc[n] = fmaf(xv.x, a0, fmaf(xv.y, a1, fmaf(xv.z, a2, fmaf(xv.w, a3, racc[n]))));
    }
  }

  int head = l >> 2, c = l & 3;
  float sa = asrc[l];   // asrc/adst are H*4 = DOUT floats
  float da = adst[l];
  #pragma unroll
  for (int n = 0; n < NPW; ++n) {
    size_t node = (size_t)(block_base + nl + n);
    float hh = acc[n];
    hW[node * DOUT + l] = hh;
    if (HAS_RES) res[node * DOUT + l] = racc[n] + Ab[l];
    float ps = hh * sa, pd = hh * da;
    ps += __shfl_xor(ps, 1); ps += __shfl_xor(ps, 2);
    pd += __shfl_xor(pd, 1); pd += __shfl_xor(pd, 2);
    if (c == 0) {
      als[node * H + head] = ps;
      ald[node * H + head] = pd;
    }
  }
}

// ---------------- fused gather: single pass, unnormalized accumulate ----------------
template<int DOUT, int H, bool HAS_RES>
__global__ __launch_bounds__(256) void gat_gather_kernel(
    const int* __restrict__ row_ptr, const int* __restrict__ col,
    const float* __restrict__ als, const float* __restrict__ ald,
    const float* __restrict__ hW,
    const float* __restrict__ bias, const float* __restrict__ g,
    const float* __restrict__ be, const float* __restrict__ res,
    float* __restrict__ out, float* __restrict__ inv_s_out)
{
  int tid = blockIdx.x * 256 + threadIdx.x;
  int node = tid / DOUT;
  int l = threadIdx.x % DOUT;   // lane within DOUT-group (aligned in wave)
  int h = l >> 2;

  int r0 = row_ptr[node], r1 = row_ptr[node + 1];
  float ald_h = ald[(size_t)node * H + h];

  float acc = 0.f, ss = 0.f;
  int e = r0;
  for (; e + 3 < r1; e += 4) {       // 4-wide for memory-level parallelism
    int s0 = col[e], s1 = col[e + 1], s2 = col[e + 2], s3 = col[e + 3];
    float av0 = als[(size_t)s0 * H + h];
    float av1 = als[(size_t)s1 * H + h];
    float av2 = als[(size_t)s2 * H + h];
    float av3 = als[(size_t)s3 * H + h];
    float hv0 = hW[(size_t)s0 * DOUT + l];
    float hv1 = hW[(size_t)s1 * DOUT + l];
    float hv2 = hW[(size_t)s2 * DOUT + l];
    float hv3 = hW[(size_t)s3 * DOUT + l];
    float lg0 = av0 + ald_h; lg0 = lg0 > 0.f ? lg0 : 0.2f * lg0;
    float lg1 = av1 + ald_h; lg1 = lg1 > 0.f ? lg1 : 0.2f * lg1;
    float lg2 = av2 + ald_h; lg2 = lg2 > 0.f ? lg2 : 0.2f * lg2;
    float lg3 = av3 + ald_h; lg3 = lg3 > 0.f ? lg3 : 0.2f * lg3;
    float e0 = __expf(lg0), e1 = __expf(lg1), e2 = __expf(lg2), e3 = __expf(lg3);
    ss += (e0 + e1) + (e2 + e3);
    acc += e0 * hv0 + e1 * hv1 + e2 * hv2 + e3 * hv3;
  }
  for (; e < r1; ++e) {
    int s0 = col[e];
    float av0 = als[(size_t)s0 * H + h];
    float hv0 = hW[(size_t)s0 * DOUT + l];
    float lg0 = av0 + ald_h; lg0 = lg0 > 0.f ? lg0 : 0.2f * lg0;
    float e0 = __expf(lg0);
    ss += e0;
    acc += e0 * hv0;
  }

  float inv = 1.f / ss;               // identical across the 4 lanes of a head
  if ((l & 3) == 0) inv_s_out[(size_t)node * H + h] = inv;

  // epilogue: normalize -> bias -> elu -> layernorm -> (+res)
  float v = acc * inv + bias[l];
  v = v > 0.f ? v : expm1f(v);
  float sum = v;
  #pragma unroll
  for (int o = DOUT / 2; o; o >>= 1) sum += __shfl_xor(sum, o);
  float mu = sum * (1.f / DOUT);
  float dv = v - mu;
  float vs = dv * dv;
  #pragma unroll
  for (int o = DOUT / 2; o; o >>= 1) vs += __shfl_xor(vs, o);
  float rstd = rsqrtf(vs * (1.f / DOUT) + 1e-5f);
  float y = dv * rstd * g[l] + be[l];
  if (HAS_RES) y += res[(size_t)node * DOUT + l];
  out[(size_t)node * DOUT + l] = y;
}

// ------- per-edge head-mean alpha + fused exp-sum (no max pass: amean in (0,1]) -------
template<int H>
__global__ __launch_bounds__(256) void amean_sumexp_kernel(
    const int* __restrict__ ei, const float* __restrict__ als,
    const float* __restrict__ ald, const float* __restrict__ inv_s,
    float* __restrict__ amean, float* __restrict__ ssum_out)
{
  __shared__ float red[4];
  int e = blockIdx.x * 256 + threadIdx.x;
  float ex = 0.f;
  if (e < EE) {
    int s = ei[e], d = ei[EE + e];
    const float* as_ = als + (size_t)s * H;
    const float* ad_ = ald + (size_t)d * H;
    const float* iv_ = inv_s + (size_t)d * H;
    float t = 0.f;
    #pragma unroll
    for (int h = 0; h < H; ++h) {
      float lg = as_[h] + ad_[h];
      lg = lg > 0.f ? lg : 0.2f * lg;
      t += __expf(lg) * iv_[h];
    }
    t *= (1.f / H);
    amean[e] = t;
    ex = __expf(t);
  }
  #pragma unroll
  for (int o = 32; o; o >>= 1) ex += __shfl_xor(ex, o);
  if ((threadIdx.x & 63) == 0) red[threadIdx.x >> 6] = ex;
  __syncthreads();
  if (threadIdx.x == 0)
    atomicAdd(ssum_out, (red[0] + red[1]) + (red[2] + red[3]));
}

__global__ __launch_bounds__(256) void write_softmax_kernel(
    const float* __restrict__ a, int n, const float* __restrict__ ssum,
    float* __restrict__ out)
{
  float inv = 1.f / *ssum;
  int i = blockIdx.x * blockDim.x + threadIdx.x;
  if (i < n) out[i] = __expf(a[i]) * inv;
}

// ---------------- per-layer driver ----------------
template<int DIN, int DOUT, int H, bool HAS_RES>
static void run_layer(const float* xin, const float* W, const float* as_,
                      const float* ad_, const float* bias, const float* Aw,
                      const float* Ab, const float* g, const float* be,
                      const int* ei, const int* row_ptr, const int* col,
                      float* hW, float* res, float* als, float* ald,
                      float* inv_s, float* amean, float* scal,
                      float* hout, float* eout, hipStream_t stream)
{
  constexpr int NPW = 8;
  constexpr int NPB = 4 * NPW * (64 / DOUT);
  hipMemsetAsync(scal, 0, sizeof(float), stream);
  gemm_al_kernel<DIN, DOUT, H, HAS_RES, NPW><<<NN / NPB, 256, 0, stream>>>(
      xin, W, as_, ad_, Aw, Ab, hW, res, als, ald);
  gat_gather_kernel<DOUT, H, HAS_RES><<<(NN * DOUT) / 256, 256, 0, stream>>>(
      row_ptr, col, als, ald, hW, bias, g, be, res, hout, inv_s);
  amean_sumexp_kernel<H><<<(EE + 255) / 256, 256, 0, stream>>>(
      ei, als, ald, inv_s, amean, scal);
  write_softmax_kernel<<<EE / 256, 256, 0, stream>>>(amean, EE, scal, eout);
}

extern "C" void kernel_launch(void* const* d_in, const int* in_sizes, int n_in,
                              void* d_out, int out_size, void* d_ws, size_t ws_size,
                              hipStream_t stream)
{
  const float* x   = (const float*)d_in[0];
  const int*   ei  = (const int*)d_in[1];
  const float* W1  = (const float*)d_in[3];
  const float* as1 = (const float*)d_in[4];
  const float* ad1 = (const float*)d_in[5];
  const float* b1  = (const float*)d_in[6];
  const float* W2  = (const float*)d_in[7];
  const float* as2 = (const float*)d_in[8];
  const float* ad2 = (const float*)d_in[9];
  const float* b2  = (const float*)d_in[10];
  const float* W3  = (const float*)d_in[11];
  const float* as3 = (const float*)d_in[12];
  const float* ad3 = (const float*)d_in[13];
  const float* b3  = (const float*)d_in[14];
  const float* A1w = (const float*)d_in[15];
  const float* A1b = (const float*)d_in[16];
  const float* A2w = (const float*)d_in[17];
  const float* A2b = (const float*)d_in[18];
  const float* g1  = (const float*)d_in[19];
  const float* be1 = (const float*)d_in[20];
  const float* g2  = (const float*)d_in[21];
  const float* be2 = (const float*)d_in[22];
  const float* g3  = (const float*)d_in[23];
  const float* be3 = (const float*)d_in[24];

  float* ws = (float*)d_ws;
  size_t off = 0;
  float* h1    = ws + off; off += (size_t)NN * 64;
  float* h2    = ws + off; off += (size_t)NN * 32;
  float* hW    = ws + off; off += (size_t)NN * 64;
  float* res   = ws + off; off += (size_t)NN * 64;
  float* als   = ws + off; off += (size_t)NN * 16;
  float* ald   = ws + off; off += (size_t)NN * 16;
  float* inv_s = ws + off; off += (size_t)NN * 16;
  float* amean = ws + off; off += (size_t)EE;
  float* scal  = ws + off; off += 16;
  int* cnt     = (int*)(ws + off); off += NN;
  int* row_ptr = (int*)(ws + off); off += NN + 4;
  int* cur     = (int*)(ws + off); off += NN;
  int* col     = (int*)(ws + off); off += ET;

  float* outh3 = (float*)d_out;
  float* oute1 = outh3 + (size_t)NN * 16;
  float* oute2 = oute1 + EE;
  float* oute3 = oute2 + EE;

  // ---- CSR build (once per call; graph-capture safe) ----
  hipMemsetAsync(cnt, 0, NN * sizeof(int), stream);
  count_kernel<<<ET / 256, 256, 0, stream>>>(ei, cnt);
  scan_kernel<<<1, 1024, 0, stream>>>(cnt, row_ptr);
  init_cur_kernel<<<NN / 256, 256, 0, stream>>>(row_ptr, cur);
  fill_kernel<<<ET / 256, 256, 0, stream>>>(ei, cur, col);

  run_layer<84, 64, 16, true>(x, W1, as1, ad1, b1, A1w, A1b, g1, be1,
                              ei, row_ptr, col, hW, res, als, ald,
                              inv_s, amean, scal, h1, oute1, stream);
  run_layer<64, 32, 8, true>(h1, W2, as2, ad2, b2, A2w, A2b, g2, be2,
                             ei, row_ptr, col, hW, res, als, ald,
                             inv_s, amean, scal, h2, oute2, stream);
  run_layer<32, 16, 4, false>(h2, W3, as3, ad3, b3, nullptr, nullptr, g3, be3,
                              ei, row_ptr, col, hW, res, als, ald,
                              inv_s, amean, scal, outh3, oute3, stream);
}

// Round 5
// 415.698 us; speedup vs baseline: 22.9389x; 1.2755x over previous
//
#include <hip/hip_runtime.h>
#include <math.h>

#define NN 65536
#define EE 1048576
#define ET (EE + NN)

#define CAPB 5120          // staging capacity per coarse bucket (mean 4352, +11.6 sigma)
#define EPB 4096           // edges per pass-1 block
#define P1B (ET / EPB)     // 272 blocks

// ---------------- CSR build via 2-pass coarse-bucket counting sort ----------------
__global__ __launch_bounds__(256) void bucket_pass1(const int* __restrict__ ei,
                                                    unsigned* __restrict__ staging,
                                                    int* __restrict__ gcnt) {
  __shared__ int hist[256];
  __shared__ int lbase[256];
  int t = threadIdx.x;
  hist[t] = 0;
  __syncthreads();
  int base = blockIdx.x * EPB;
  unsigned pk[16];
  int bk[16];
  #pragma unroll
  for (int j = 0; j < 16; ++j) {
    int e = base + j * 256 + t;
    int s, d;
    if (e < EE) { s = ei[e]; d = ei[EE + e]; } else { s = d = e - EE; }
    pk[j] = ((unsigned)s << 8) | (unsigned)(d & 255);
    bk[j] = d >> 8;
    atomicAdd(&hist[bk[j]], 1);
  }
  __syncthreads();
  lbase[t] = atomicAdd(&gcnt[t], hist[t]);   // reserve contiguous chunk per bucket
  __syncthreads();
  #pragma unroll
  for (int j = 0; j < 16; ++j) {
    int pos = atomicAdd(&lbase[bk[j]], 1);
    staging[(size_t)bk[j] * CAPB + pos] = pk[j];
  }
}

__global__ __launch_bounds__(256) void bucket_pass2(const unsigned* __restrict__ staging,
                                                    const int* __restrict__ gcnt,
                                                    int* __restrict__ row_ptr,
                                                    int* __restrict__ col) {
  __shared__ int pref[256];
  __shared__ int hist[256];
  __shared__ int loc[256];
  __shared__ int cnt2[256];
  __shared__ unsigned lin[CAPB];
  __shared__ unsigned short lout[CAPB];
  int t = threadIdx.x, b = blockIdx.x;

  pref[t] = gcnt[t];
  hist[t] = 0;
  __syncthreads();
  for (int off = 1; off < 256; off <<= 1) {      // inclusive scan of bucket counts
    int v = (t >= off) ? pref[t - off] : 0;
    __syncthreads();
    pref[t] += v;
    __syncthreads();
  }
  int rowbase = (b > 0) ? pref[b - 1] : 0;
  int nb = gcnt[b];

  for (int i = t; i < nb; i += 256) {
    unsigned v = staging[(size_t)b * CAPB + i];
    lin[i] = v;
    atomicAdd(&hist[v & 255], 1);
  }
  __syncthreads();
  loc[t] = hist[t];
  __syncthreads();
  for (int off = 1; off < 256; off <<= 1) {      // inclusive scan of local hist
    int v = (t >= off) ? loc[t - off] : 0;
    __syncthreads();
    loc[t] += v;
    __syncthreads();
  }
  int excl = loc[t] - hist[t];
  row_ptr[b * 256 + t] = rowbase + excl;
  cnt2[t] = excl;
  if (b == 255 && t == 255) row_ptr[NN] = rowbase + nb;
  __syncthreads();
  for (int i = t; i < nb; i += 256) {
    unsigned v = lin[i];
    int r = atomicAdd(&cnt2[v & 255], 1);
    lout[r] = (unsigned short)(v >> 8);
  }
  __syncthreads();
  for (int i = t; i < nb; i += 256) col[rowbase + i] = (int)lout[i];  // coalesced
}

// -------- dense: h = x@W, al_s/al_d, residual; register-blocked over nodes --------
template<int DIN, int DOUT, int H, bool HAS_RES, int NPW>
__global__ __launch_bounds__(256) void gemm_al_kernel(
    const float* __restrict__ xin, const float* __restrict__ W,
    const float* __restrict__ asrc, const float* __restrict__ adst,
    const float* __restrict__ Aw, const float* __restrict__ Ab,
    float* __restrict__ hW, float* __restrict__ res,
    float* __restrict__ als, float* __restrict__ ald)
{
  constexpr int GPW = 64 / DOUT;
  constexpr int NPB = 4 * NPW * GPW;   // nodes per block (4 waves)
  constexpr int DINP = DIN + 4;        // padded LDS stride
  __shared__ float xs[NPB][DINP];

  int wave = threadIdx.x >> 6;
  int lane = threadIdx.x & 63;
  int l = lane % DOUT;
  int sub = lane / DOUT;
  int block_base = blockIdx.x * NPB;

  {
    constexpr int NV = NPB * DIN / 4;
    const float4* xin4 = (const float4*)(xin + (size_t)block_base * DIN);
    for (int i = threadIdx.x; i < NV; i += 256) {
      float4 v = xin4[i];
      int flat = i * 4;
      int nd = flat / DIN, k = flat % DIN;
      *(float4*)&xs[nd][k] = v;
    }
  }
  __syncthreads();

  int nl = wave * (NPW * GPW) + sub * NPW;
  float acc[NPW], racc[NPW];
  #pragma unroll
  for (int n = 0; n < NPW; ++n) { acc[n] = 0.f; racc[n] = 0.f; }

  for (int k = 0; k < DIN; k += 4) {
    float w0 = W[(k + 0) * DOUT + l];
    float w1 = W[(k + 1) * DOUT + l];
    float w2 = W[(k + 2) * DOUT + l];
    float w3 = W[(k + 3) * DOUT + l];
    float a0 = 0.f, a1 = 0.f, a2 = 0.f, a3 = 0.f;
    if (HAS_RES) {
      a0 = Aw[(k + 0) * DOUT + l];
      a1 = Aw[(k + 1) * DOUT + l];
      a2 = Aw[(k + 2) * DOUT + l];
      a3 = Aw[(k + 3) * DOUT + l];
    }
    #pragma unroll
    for (int n = 0; n < NPW; ++n) {
      float4 xv = *(const float4*)&xs[nl + n][k];
      acc[n] = fmaf(xv.x, w0, fmaf(xv.y, w1, fmaf(xv.z, w2, fmaf(xv.w, w3, acc[n]))));
      if (HAS_RES)
        racc[n] = fmaf(xv.x, a0, fmaf(xv.y, a1, fmaf(xv.z, a2, fmaf(xv.w, a3, racc[n]))));
    }
  }

  int head = l >> 2, c = l & 3;
  float sa = asrc[l];
  float da = adst[l];
  #pragma unroll
  for (int n = 0; n < NPW; ++n) {
    size_t node = (size_t)(block_base + nl + n);
    float hh = acc[n];
    hW[node * DOUT + l] = hh;
    if (HAS_RES) res[node * DOUT + l] = racc[n] + Ab[l];
    float ps = hh * sa, pd = hh * da;
    ps += __shfl_xor(ps, 1); ps += __shfl_xor(ps, 2);
    pd += __shfl_xor(pd, 1); pd += __shfl_xor(pd, 2);
    if (c == 0) {
      als[node * H + head] = ps;
      ald[node * H + head] = pd;
    }
  }
}

// ---------------- fused gather: single pass, unnormalized accumulate ----------------
template<int DOUT, int H, bool HAS_RES>
__global__ __launch_bounds__(256) void gat_gather_kernel(
    const int* __restrict__ row_ptr, const int* __restrict__ col,
    const float* __restrict__ als, const float* __restrict__ ald,
    const float* __restrict__ hW,
    const float* __restrict__ bias, const float* __restrict__ g,
    const float* __restrict__ be, const float* __restrict__ res,
    float* __restrict__ out, float* __restrict__ inv_s_out)
{
  int tid = blockIdx.x * 256 + threadIdx.x;
  int node = tid / DOUT;
  int l = threadIdx.x % DOUT;
  int h = l >> 2;

  int r0 = row_ptr[node], r1 = row_ptr[node + 1];
  float ald_h = ald[(size_t)node * H + h];

  float acc = 0.f, ss = 0.f;
  int e = r0;
  for (; e + 3 < r1; e += 4) {
    int s0 = col[e], s1 = col[e + 1], s2 = col[e + 2], s3 = col[e + 3];
    float av0 = als[(size_t)s0 * H + h];
    float av1 = als[(size_t)s1 * H + h];
    float av2 = als[(size_t)s2 * H + h];
    float av3 = als[(size_t)s3 * H + h];
    float hv0 = hW[(size_t)s0 * DOUT + l];
    float hv1 = hW[(size_t)s1 * DOUT + l];
    float hv2 = hW[(size_t)s2 * DOUT + l];
    float hv3 = hW[(size_t)s3 * DOUT + l];
    float lg0 = av0 + ald_h; lg0 = lg0 > 0.f ? lg0 : 0.2f * lg0;
    float lg1 = av1 + ald_h; lg1 = lg1 > 0.f ? lg1 : 0.2f * lg1;
    float lg2 = av2 + ald_h; lg2 = lg2 > 0.f ? lg2 : 0.2f * lg2;
    float lg3 = av3 + ald_h; lg3 = lg3 > 0.f ? lg3 : 0.2f * lg3;
    float e0 = __expf(lg0), e1 = __expf(lg1), e2 = __expf(lg2), e3 = __expf(lg3);
    ss += (e0 + e1) + (e2 + e3);
    acc += e0 * hv0 + e1 * hv1 + e2 * hv2 + e3 * hv3;
  }
  for (; e < r1; ++e) {
    int s0 = col[e];
    float av0 = als[(size_t)s0 * H + h];
    float hv0 = hW[(size_t)s0 * DOUT + l];
    float lg0 = av0 + ald_h; lg0 = lg0 > 0.f ? lg0 : 0.2f * lg0;
    float e0 = __expf(lg0);
    ss += e0;
    acc += e0 * hv0;
  }

  float inv = 1.f / ss;
  if ((l & 3) == 0) inv_s_out[(size_t)node * H + h] = inv;

  float v = acc * inv + bias[l];
  v = v > 0.f ? v : expm1f(v);
  float sum = v;
  #pragma unroll
  for (int o = DOUT / 2; o; o >>= 1) sum += __shfl_xor(sum, o);
  float mu = sum * (1.f / DOUT);
  float dv = v - mu;
  float vs = dv * dv;
  #pragma unroll
  for (int o = DOUT / 2; o; o >>= 1) vs += __shfl_xor(vs, o);
  float rstd = rsqrtf(vs * (1.f / DOUT) + 1e-5f);
  float y = dv * rstd * g[l] + be[l];
  if (HAS_RES) y += res[(size_t)node * DOUT + l];
  out[(size_t)node * DOUT + l] = y;
}

// ------- per-edge head-mean alpha + fused exp-sum (no max pass: amean in (0,1]) -------
template<int H>
__global__ __launch_bounds__(256) void amean_sumexp_kernel(
    const int* __restrict__ ei, const float* __restrict__ als,
    const float* __restrict__ ald, const float* __restrict__ inv_s,
    float* __restrict__ amean, float* __restrict__ ssum_out)
{
  __shared__ float red[4];
  int e = blockIdx.x * 256 + threadIdx.x;
  float ex = 0.f;
  if (e < EE) {
    int s = ei[e], d = ei[EE + e];
    const float* as_ = als + (size_t)s * H;
    const float* ad_ = ald + (size_t)d * H;
    const float* iv_ = inv_s + (size_t)d * H;
    float t = 0.f;
    #pragma unroll
    for (int h = 0; h < H; ++h) {
      float lg = as_[h] + ad_[h];
      lg = lg > 0.f ? lg : 0.2f * lg;
      t += __expf(lg) * iv_[h];
    }
    t *= (1.f / H);
    amean[e] = t;
    ex = __expf(t);
  }
  #pragma unroll
  for (int o = 32; o; o >>= 1) ex += __shfl_xor(ex, o);
  if ((threadIdx.x & 63) == 0) red[threadIdx.x >> 6] = ex;
  __syncthreads();
  if (threadIdx.x == 0)
    atomicAdd(ssum_out, (red[0] + red[1]) + (red[2] + red[3]));
}

__global__ __launch_bounds__(256) void write_softmax_kernel(
    const float* __restrict__ a, int n, const float* __restrict__ ssum,
    float* __restrict__ out)
{
  float inv = 1.f / *ssum;
  int i = blockIdx.x * blockDim.x + threadIdx.x;
  if (i < n) out[i] = __expf(a[i]) * inv;
}

// ---------------- per-layer driver ----------------
template<int DIN, int DOUT, int H, bool HAS_RES>
static void run_layer(const float* xin, const float* W, const float* as_,
                      const float* ad_, const float* bias, const float* Aw,
                      const float* Ab, const float* g, const float* be,
                      const int* ei, const int* row_ptr, const int* col,
                      float* hW, float* res, float* als, float* ald,
                      float* inv_s, float* amean, float* scal,
                      float* hout, float* eout, hipStream_t stream)
{
  constexpr int NPW = 8;
  constexpr int NPB = 4 * NPW * (64 / DOUT);
  hipMemsetAsync(scal, 0, sizeof(float), stream);
  gemm_al_kernel<DIN, DOUT, H, HAS_RES, NPW><<<NN / NPB, 256, 0, stream>>>(
      xin, W, as_, ad_, Aw, Ab, hW, res, als, ald);
  gat_gather_kernel<DOUT, H, HAS_RES><<<(NN * DOUT) / 256, 256, 0, stream>>>(
      row_ptr, col, als, ald, hW, bias, g, be, res, hout, inv_s);
  amean_sumexp_kernel<H><<<(EE + 255) / 256, 256, 0, stream>>>(
      ei, als, ald, inv_s, amean, scal);
  write_softmax_kernel<<<EE / 256, 256, 0, stream>>>(amean, EE, scal, eout);
}

extern "C" void kernel_launch(void* const* d_in, const int* in_sizes, int n_in,
                              void* d_out, int out_size, void* d_ws, size_t ws_size,
                              hipStream_t stream)
{
  const float* x   = (const float*)d_in[0];
  const int*   ei  = (const int*)d_in[1];
  const float* W1  = (const float*)d_in[3];
  const float* as1 = (const float*)d_in[4];
  const float* ad1 = (const float*)d_in[5];
  const float* b1  = (const float*)d_in[6];
  const float* W2  = (const float*)d_in[7];
  const float* as2 = (const float*)d_in[8];
  const float* ad2 = (const float*)d_in[9];
  const float* b2  = (const float*)d_in[10];
  const float* W3  = (const float*)d_in[11];
  const float* as3 = (const float*)d_in[12];
  const float* ad3 = (const float*)d_in[13];
  const float* b3  = (const float*)d_in[14];
  const float* A1w = (const float*)d_in[15];
  const float* A1b = (const float*)d_in[16];
  const float* A2w = (const float*)d_in[17];
  const float* A2b = (const float*)d_in[18];
  const float* g1  = (const float*)d_in[19];
  const float* be1 = (const float*)d_in[20];
  const float* g2  = (const float*)d_in[21];
  const float* be2 = (const float*)d_in[22];
  const float* g3  = (const float*)d_in[23];
  const float* be3 = (const float*)d_in[24];

  float* ws = (float*)d_ws;
  size_t off = 0;
  float* h1       = ws + off; off += (size_t)NN * 64;
  float* h2       = ws + off; off += (size_t)NN * 32;
  float* hW       = ws + off; off += (size_t)NN * 64;
  float* res      = ws + off; off += (size_t)NN * 64;
  float* als      = ws + off; off += (size_t)NN * 16;
  float* ald      = ws + off; off += (size_t)NN * 16;
  float* inv_s    = ws + off; off += (size_t)NN * 16;
  float* amean    = ws + off; off += (size_t)EE;
  float* scal     = ws + off; off += 16;
  int* row_ptr    = (int*)(ws + off); off += NN + 4;
  int* col        = (int*)(ws + off); off += ET;
  int* gcnt       = (int*)(ws + off); off += 256;
  unsigned* staging = (unsigned*)(ws + off); off += (size_t)256 * CAPB;

  float* outh3 = (float*)d_out;
  float* oute1 = outh3 + (size_t)NN * 16;
  float* oute2 = oute1 + EE;
  float* oute3 = oute2 + EE;

  // ---- CSR build via coarse-bucket sort (graph-capture safe) ----
  hipMemsetAsync(gcnt, 0, 256 * sizeof(int), stream);
  bucket_pass1<<<P1B, 256, 0, stream>>>(ei, staging, gcnt);
  bucket_pass2<<<256, 256, 0, stream>>>(staging, gcnt, row_ptr, col);

  run_layer<84, 64, 16, true>(x, W1, as1, ad1, b1, A1w, A1b, g1, be1,
                              ei, row_ptr, col, hW, res, als, ald,
                              inv_s, amean, scal, h1, oute1, stream);
  run_layer<64, 32, 8, true>(h1, W2, as2, ad2, b2, A2w, A2b, g2, be2,
                             ei, row_ptr, col, hW, res, als, ald,
                             inv_s, amean, scal, h2, oute2, stream);
  run_layer<32, 16, 4, false>(h2, W3, as3, ad3, b3, nullptr, nullptr, g3, be3,
                              ei, row_ptr, col, hW, res, als, ald,
                              inv_s, amean, scal, outh3, oute3, stream);
}

// Round 6
// 377.752 us; speedup vs baseline: 25.2431x; 1.1005x over previous
//
#include <hip/hip_runtime.h>
#include <math.h>

#define NN 65536
#define EE 1048576
#define ET (EE + NN)

#define CAPB 5120          // staging capacity per coarse bucket (mean 4352, +11.6 sigma)
#define EPB 4096           // edges per pass-1 block
#define P1B (ET / EPB)     // 272 blocks

// ---------------- CSR build via 2-pass coarse-bucket counting sort ----------------
__global__ __launch_bounds__(256) void bucket_pass1(const int* __restrict__ ei,
                                                    unsigned* __restrict__ staging,
                                                    int* __restrict__ gcnt) {
  __shared__ int hist[256];
  __shared__ int lbase[256];
  int t = threadIdx.x;
  hist[t] = 0;
  __syncthreads();
  int base = blockIdx.x * EPB;
  unsigned pk[16];
  int bk[16];
  #pragma unroll
  for (int j = 0; j < 16; ++j) {
    int e = base + j * 256 + t;
    int s, d;
    if (e < EE) { s = ei[e]; d = ei[EE + e]; } else { s = d = e - EE; }
    pk[j] = ((unsigned)s << 8) | (unsigned)(d & 255);
    bk[j] = d >> 8;
    atomicAdd(&hist[bk[j]], 1);
  }
  __syncthreads();
  lbase[t] = atomicAdd(&gcnt[t], hist[t]);   // reserve contiguous chunk per bucket
  __syncthreads();
  #pragma unroll
  for (int j = 0; j < 16; ++j) {
    int pos = atomicAdd(&lbase[bk[j]], 1);
    staging[(size_t)bk[j] * CAPB + pos] = pk[j];
  }
}

__global__ __launch_bounds__(256) void bucket_pass2(const unsigned* __restrict__ staging,
                                                    const int* __restrict__ gcnt,
                                                    int* __restrict__ row_ptr,
                                                    int* __restrict__ col) {
  __shared__ int pref[256];
  __shared__ int hist[256];
  __shared__ int loc[256];
  __shared__ int cnt2[256];
  __shared__ unsigned lin[CAPB];
  __shared__ unsigned short lout[CAPB];
  int t = threadIdx.x, b = blockIdx.x;

  pref[t] = gcnt[t];
  hist[t] = 0;
  __syncthreads();
  for (int off = 1; off < 256; off <<= 1) {      // inclusive scan of bucket counts
    int v = (t >= off) ? pref[t - off] : 0;
    __syncthreads();
    pref[t] += v;
    __syncthreads();
  }
  int rowbase = (b > 0) ? pref[b - 1] : 0;
  int nb = gcnt[b];

  for (int i = t; i < nb; i += 256) {
    unsigned v = staging[(size_t)b * CAPB + i];
    lin[i] = v;
    atomicAdd(&hist[v & 255], 1);
  }
  __syncthreads();
  loc[t] = hist[t];
  __syncthreads();
  for (int off = 1; off < 256; off <<= 1) {      // inclusive scan of local hist
    int v = (t >= off) ? loc[t - off] : 0;
    __syncthreads();
    loc[t] += v;
    __syncthreads();
  }
  int excl = loc[t] - hist[t];
  row_ptr[b * 256 + t] = rowbase + excl;
  cnt2[t] = excl;
  if (b == 255 && t == 255) row_ptr[NN] = rowbase + nb;
  __syncthreads();
  for (int i = t; i < nb; i += 256) {
    unsigned v = lin[i];
    int r = atomicAdd(&cnt2[v & 255], 1);
    lout[r] = (unsigned short)(v >> 8);
  }
  __syncthreads();
  for (int i = t; i < nb; i += 256) col[rowbase + i] = (int)lout[i];  // coalesced
}

// -------- dense: h = x@W, al_s/al_d, residual; register-blocked over nodes --------
// hW is written as bf16 (RNE) for the gather; al uses full f32 h.
template<int DIN, int DOUT, int H, bool HAS_RES, int NPW>
__global__ __launch_bounds__(256) void gemm_al_kernel(
    const float* __restrict__ xin, const float* __restrict__ W,
    const float* __restrict__ asrc, const float* __restrict__ adst,
    const float* __restrict__ Aw, const float* __restrict__ Ab,
    unsigned short* __restrict__ hw16, float* __restrict__ res,
    float* __restrict__ als, float* __restrict__ ald)
{
  constexpr int GPW = 64 / DOUT;
  constexpr int NPB = 4 * NPW * GPW;   // nodes per block (4 waves)
  constexpr int DINP = DIN + 4;        // padded LDS stride
  __shared__ float xs[NPB][DINP];

  int wave = threadIdx.x >> 6;
  int lane = threadIdx.x & 63;
  int l = lane % DOUT;
  int sub = lane / DOUT;
  int block_base = blockIdx.x * NPB;

  {
    constexpr int NV = NPB * DIN / 4;
    const float4* xin4 = (const float4*)(xin + (size_t)block_base * DIN);
    for (int i = threadIdx.x; i < NV; i += 256) {
      float4 v = xin4[i];
      int flat = i * 4;
      int nd = flat / DIN, k = flat % DIN;
      *(float4*)&xs[nd][k] = v;
    }
  }
  __syncthreads();

  int nl = wave * (NPW * GPW) + sub * NPW;
  float acc[NPW], racc[NPW];
  #pragma unroll
  for (int n = 0; n < NPW; ++n) { acc[n] = 0.f; racc[n] = 0.f; }

  for (int k = 0; k < DIN; k += 4) {
    float w0 = W[(k + 0) * DOUT + l];
    float w1 = W[(k + 1) * DOUT + l];
    float w2 = W[(k + 2) * DOUT + l];
    float w3 = W[(k + 3) * DOUT + l];
    float a0 = 0.f, a1 = 0.f, a2 = 0.f, a3 = 0.f;
    if (HAS_RES) {
      a0 = Aw[(k + 0) * DOUT + l];
      a1 = Aw[(k + 1) * DOUT + l];
      a2 = Aw[(k + 2) * DOUT + l];
      a3 = Aw[(k + 3) * DOUT + l];
    }
    #pragma unroll
    for (int n = 0; n < NPW; ++n) {
      float4 xv = *(const float4*)&xs[nl + n][k];
      acc[n] = fmaf(xv.x, w0, fmaf(xv.y, w1, fmaf(xv.z, w2, fmaf(xv.w, w3, acc[n]))));
      if (HAS_RES)
        racc[n] = fmaf(xv.x, a0, fmaf(xv.y, a1, fmaf(xv.z, a2, fmaf(xv.w, a3, racc[n]))));
    }
  }

  int head = l >> 2, c = l & 3;
  float sa = asrc[l];
  float da = adst[l];
  #pragma unroll
  for (int n = 0; n < NPW; ++n) {
    size_t node = (size_t)(block_base + nl + n);
    float hh = acc[n];
    unsigned u = __float_as_uint(hh);
    hw16[node * DOUT + l] = (unsigned short)((u + 0x7fffu + ((u >> 16) & 1u)) >> 16);
    if (HAS_RES) res[node * DOUT + l] = racc[n] + Ab[l];
    float ps = hh * sa, pd = hh * da;
    ps += __shfl_xor(ps, 1); ps += __shfl_xor(ps, 2);
    pd += __shfl_xor(pd, 1); pd += __shfl_xor(pd, 2);
    if (c == 0) {
      als[node * H + head] = ps;
      ald[node * H + head] = pd;
    }
  }
}

// ---------------- fused gather: bf16x2 channels, DOUT/2 lanes per node ----------------
template<int DOUT, int H, bool HAS_RES>
__global__ __launch_bounds__(256) void gat_gather_kernel(
    const int* __restrict__ row_ptr, const int* __restrict__ col,
    const float* __restrict__ als, const float* __restrict__ ald,
    const unsigned* __restrict__ hw2,   // bf16x2: channels (2l, 2l+1)
    const float* __restrict__ bias, const float* __restrict__ g,
    const float* __restrict__ be, const float* __restrict__ res,
    float* __restrict__ out, float* __restrict__ inv_s_out)
{
  constexpr int G = DOUT / 2;          // lanes per node
  int tid = blockIdx.x * 256 + threadIdx.x;
  int node = tid / G;
  int l = threadIdx.x % G;             // group lane: channels 2l, 2l+1
  int h = l >> 1;                      // head (2 lanes per head)

  int r0 = row_ptr[node], r1 = row_ptr[node + 1];
  float ald_h = ald[node * H + h];

  float acc0 = 0.f, acc1 = 0.f, ss = 0.f;
  int e = r0;
  for (; e + 3 < r1; e += 4) {
    int s0 = col[e], s1 = col[e + 1], s2 = col[e + 2], s3 = col[e + 3];
    float av0 = als[s0 * H + h];
    float av1 = als[s1 * H + h];
    float av2 = als[s2 * H + h];
    float av3 = als[s3 * H + h];
    unsigned p0 = hw2[s0 * G + l];
    unsigned p1 = hw2[s1 * G + l];
    unsigned p2 = hw2[s2 * G + l];
    unsigned p3 = hw2[s3 * G + l];
    float lg0 = av0 + ald_h; lg0 = lg0 > 0.f ? lg0 : 0.2f * lg0;
    float lg1 = av1 + ald_h; lg1 = lg1 > 0.f ? lg1 : 0.2f * lg1;
    float lg2 = av2 + ald_h; lg2 = lg2 > 0.f ? lg2 : 0.2f * lg2;
    float lg3 = av3 + ald_h; lg3 = lg3 > 0.f ? lg3 : 0.2f * lg3;
    float e0 = __expf(lg0), e1 = __expf(lg1), e2 = __expf(lg2), e3 = __expf(lg3);
    ss += (e0 + e1) + (e2 + e3);
    acc0 += e0 * __uint_as_float(p0 << 16) + e1 * __uint_as_float(p1 << 16)
          + e2 * __uint_as_float(p2 << 16) + e3 * __uint_as_float(p3 << 16);
    acc1 += e0 * __uint_as_float(p0 & 0xffff0000u) + e1 * __uint_as_float(p1 & 0xffff0000u)
          + e2 * __uint_as_float(p2 & 0xffff0000u) + e3 * __uint_as_float(p3 & 0xffff0000u);
  }
  for (; e < r1; ++e) {
    int s0 = col[e];
    float av0 = als[s0 * H + h];
    unsigned p0 = hw2[s0 * G + l];
    float lg0 = av0 + ald_h; lg0 = lg0 > 0.f ? lg0 : 0.2f * lg0;
    float e0 = __expf(lg0);
    ss += e0;
    acc0 += e0 * __uint_as_float(p0 << 16);
    acc1 += e0 * __uint_as_float(p0 & 0xffff0000u);
  }

  float inv = 1.f / ss;                // identical across the 2 lanes of a head
  if ((l & 1) == 0) inv_s_out[node * H + h] = inv;

  // epilogue: normalize -> bias -> elu -> layernorm -> (+res), 2 channels/lane
  float2 bb = ((const float2*)bias)[l];
  float v0 = acc0 * inv + bb.x;
  float v1 = acc1 * inv + bb.y;
  v0 = v0 > 0.f ? v0 : expm1f(v0);
  v1 = v1 > 0.f ? v1 : expm1f(v1);
  float sum = v0 + v1;
  #pragma unroll
  for (int o = G / 2; o; o >>= 1) sum += __shfl_xor(sum, o);
  float mu = sum * (1.f / DOUT);
  float d0 = v0 - mu, d1 = v1 - mu;
  float vs = d0 * d0 + d1 * d1;
  #pragma unroll
  for (int o = G / 2; o; o >>= 1) vs += __shfl_xor(vs, o);
  float rstd = rsqrtf(vs * (1.f / DOUT) + 1e-5f);
  float2 gg = ((const float2*)g)[l];
  float2 ee = ((const float2*)be)[l];
  float y0 = d0 * rstd * gg.x + ee.x;
  float y1 = d1 * rstd * gg.y + ee.y;
  if (HAS_RES) {
    float2 rr = ((const float2*)res)[node * G + l];
    y0 += rr.x; y1 += rr.y;
  }
  ((float2*)out)[node * G + l] = make_float2(y0, y1);
}

// ------- per-edge head-mean alpha + fused exp-sum (no max pass: amean in (0,1]) -------
template<int H>
__global__ __launch_bounds__(256) void amean_sumexp_kernel(
    const int* __restrict__ ei, const float* __restrict__ als,
    const float* __restrict__ ald, const float* __restrict__ inv_s,
    float* __restrict__ amean, float* __restrict__ ssum_out)
{
  __shared__ float red[4];
  int e = blockIdx.x * 256 + threadIdx.x;
  float ex = 0.f;
  if (e < EE) {
    int s = ei[e], d = ei[EE + e];
    const float* as_ = als + (size_t)s * H;
    const float* ad_ = ald + (size_t)d * H;
    const float* iv_ = inv_s + (size_t)d * H;
    float t = 0.f;
    #pragma unroll
    for (int h = 0; h < H; ++h) {
      float lg = as_[h] + ad_[h];
      lg = lg > 0.f ? lg : 0.2f * lg;
      t += __expf(lg) * iv_[h];
    }
    t *= (1.f / H);
    amean[e] = t;
    ex = __expf(t);
  }
  #pragma unroll
  for (int o = 32; o; o >>= 1) ex += __shfl_xor(ex, o);
  if ((threadIdx.x & 63) == 0) red[threadIdx.x >> 6] = ex;
  __syncthreads();
  if (threadIdx.x == 0)
    atomicAdd(ssum_out, (red[0] + red[1]) + (red[2] + red[3]));
}

__global__ __launch_bounds__(256) void write_softmax_kernel(
    const float* __restrict__ a, int n, const float* __restrict__ ssum,
    float* __restrict__ out)
{
  float inv = 1.f / *ssum;
  int i = blockIdx.x * blockDim.x + threadIdx.x;
  if (i < n) out[i] = __expf(a[i]) * inv;
}

// ---------------- per-layer driver ----------------
template<int DIN, int DOUT, int H, bool HAS_RES>
static void run_layer(const float* xin, const float* W, const float* as_,
                      const float* ad_, const float* bias, const float* Aw,
                      const float* Ab, const float* g, const float* be,
                      const int* ei, const int* row_ptr, const int* col,
                      unsigned short* hw16, float* res, float* als, float* ald,
                      float* inv_s, float* amean, float* scal,
                      float* hout, float* eout, hipStream_t stream)
{
  constexpr int NPW = 8;
  constexpr int NPB = 4 * NPW * (64 / DOUT);
  constexpr int G = DOUT / 2;
  hipMemsetAsync(scal, 0, sizeof(float), stream);
  gemm_al_kernel<DIN, DOUT, H, HAS_RES, NPW><<<NN / NPB, 256, 0, stream>>>(
      xin, W, as_, ad_, Aw, Ab, hw16, res, als, ald);
  gat_gather_kernel<DOUT, H, HAS_RES><<<(NN * G) / 256, 256, 0, stream>>>(
      row_ptr, col, als, ald, (const unsigned*)hw16, bias, g, be, res, hout, inv_s);
  amean_sumexp_kernel<H><<<(EE + 255) / 256, 256, 0, stream>>>(
      ei, als, ald, inv_s, amean, scal);
  write_softmax_kernel<<<EE / 256, 256, 0, stream>>>(amean, EE, scal, eout);
}

extern "C" void kernel_launch(void* const* d_in, const int* in_sizes, int n_in,
                              void* d_out, int out_size, void* d_ws, size_t ws_size,
                              hipStream_t stream)
{
  const float* x   = (const float*)d_in[0];
  const int*   ei  = (const int*)d_in[1];
  const float* W1  = (const float*)d_in[3];
  const float* as1 = (const float*)d_in[4];
  const float* ad1 = (const float*)d_in[5];
  const float* b1  = (const float*)d_in[6];
  const float* W2  = (const float*)d_in[7];
  const float* as2 = (const float*)d_in[8];
  const float* ad2 = (const float*)d_in[9];
  const float* b2  = (const float*)d_in[10];
  const float* W3  = (const float*)d_in[11];
  const float* as3 = (const float*)d_in[12];
  const float* ad3 = (const float*)d_in[13];
  const float* b3  = (const float*)d_in[14];
  const float* A1w = (const float*)d_in[15];
  const float* A1b = (const float*)d_in[16];
  const float* A2w = (const float*)d_in[17];
  const float* A2b = (const float*)d_in[18];
  const float* g1  = (const float*)d_in[19];
  const float* be1 = (const float*)d_in[20];
  const float* g2  = (const float*)d_in[21];
  const float* be2 = (const float*)d_in[22];
  const float* g3  = (const float*)d_in[23];
  const float* be3 = (const float*)d_in[24];

  float* ws = (float*)d_ws;
  size_t off = 0;
  float* h1       = ws + off; off += (size_t)NN * 64;
  float* h2       = ws + off; off += (size_t)NN * 32;
  unsigned short* hw16 = (unsigned short*)(ws + off); off += (size_t)NN * 32;
  float* res      = ws + off; off += (size_t)NN * 64;
  float* als      = ws + off; off += (size_t)NN * 16;
  float* ald      = ws + off; off += (size_t)NN * 16;
  float* inv_s    = ws + off; off += (size_t)NN * 16;
  float* amean    = ws + off; off += (size_t)EE;
  float* scal     = ws + off; off += 16;
  int* row_ptr    = (int*)(ws + off); off += NN + 4;
  int* col        = (int*)(ws + off); off += ET;
  int* gcnt       = (int*)(ws + off); off += 256;
  unsigned* staging = (unsigned*)(ws + off); off += (size_t)256 * CAPB;

  float* outh3 = (float*)d_out;
  float* oute1 = outh3 + (size_t)NN * 16;
  float* oute2 = oute1 + EE;
  float* oute3 = oute2 + EE;

  // ---- CSR build via coarse-bucket sort (graph-capture safe) ----
  hipMemsetAsync(gcnt, 0, 256 * sizeof(int), stream);
  bucket_pass1<<<P1B, 256, 0, stream>>>(ei, staging, gcnt);
  bucket_pass2<<<256, 256, 0, stream>>>(staging, gcnt, row_ptr, col);

  run_layer<84, 64, 16, true>(x, W1, as1, ad1, b1, A1w, A1b, g1, be1,
                              ei, row_ptr, col, hw16, res, als, ald,
                              inv_s, amean, scal, h1, oute1, stream);
  run_layer<64, 32, 8, true>(h1, W2, as2, ad2, b2, A2w, A2b, g2, be2,
                             ei, row_ptr, col, hw16, res, als, ald,
                             inv_s, amean, scal, h2, oute2, stream);
  run_layer<32, 16, 4, false>(h2, W3, as3, ad3, b3, nullptr, nullptr, g3, be3,
                              ei, row_ptr, col, hw16, res, als, ald,
                              inv_s, amean, scal, outh3, oute3, stream);
}